// Round 1
// baseline (4565.210 us; speedup 1.0000x reference)
//
#include <hip/hip_runtime.h>

#define DD 64

// Build symmetric coupling matrix M (64x64) from packed strict-lower-triangle Q.
// np.tril_indices(64,-1) row-major: index of (r,c), r>c, is r*(r-1)/2 + c.
__global__ void build_M_kernel(const float* __restrict__ Q, float* __restrict__ M) {
    int idx = blockIdx.x * 256 + threadIdx.x;
    if (idx < DD * DD) {
        int r = idx >> 6;
        int c = idx & 63;
        float v = 0.0f;
        if (r > c)      v = Q[(r * (r - 1)) / 2 + c];
        else if (c > r) v = Q[(c * (c - 1)) / 2 + r];
        M[idx] = v;
    }
}

// One thread per chain. x[64] lives in VGPRs (all indexing static via full
// unroll). M/delta reads are wave-uniform -> scalar loads (s_load_dwordx16),
// so the 64-FMA dot runs VALU-only with an SGPR source operand.
__global__ __launch_bounds__(256, 4) void ising_main(
    const float* __restrict__ M,       // 64x64 symmetric, diag 0 (in d_ws)
    const float* __restrict__ delta,   // 64
    const float* __restrict__ x0,      // B*64
    const float* __restrict__ u,       // L*B*64
    const int* __restrict__ n_layers_p,
    const int* __restrict__ const_p,
    float* __restrict__ out,           // B*64 (z) then B (energy)
    int B)
{
    const int b = blockIdx.x * 256 + threadIdx.x;
    if (b >= B) return;
    const int L = n_layers_p[0];
    const float c = (float)const_p[0];

    float x[DD];
    {
        const float4* xin = (const float4*)(x0 + (size_t)b * DD);
#pragma unroll
        for (int i = 0; i < DD / 4; ++i) {
            float4 v = xin[i];
            x[4 * i + 0] = v.x; x[4 * i + 1] = v.y;
            x[4 * i + 2] = v.z; x[4 * i + 3] = v.w;
        }
    }

    for (int l = 0; l < L; ++l) {
        const float4* ub = (const float4*)(u + ((size_t)l * B + b) * DD);
#pragma unroll
        for (int kq = 0; kq < DD / 4; ++kq) {
            float4 uv = ub[kq];
            float uvals[4] = {uv.x, uv.y, uv.z, uv.w};
#pragma unroll
            for (int ki = 0; ki < 4; ++ki) {
                const int k = kq * 4 + ki;
                const float* Mr = M + k * DD;
                // 4-way split accumulation to break the FMA dependence chain
                float a0 = 0.f, a1 = 0.f, a2 = 0.f, a3 = 0.f;
#pragma unroll
                for (int j = 0; j < DD; j += 4) {
                    a0 = fmaf(Mr[j + 0], x[j + 0], a0);
                    a1 = fmaf(Mr[j + 1], x[j + 1], a1);
                    a2 = fmaf(Mr[j + 2], x[j + 2], a2);
                    a3 = fmaf(Mr[j + 3], x[j + 3], a3);
                }
                float alpha = delta[k] + ((a0 + a1) + (a2 + a3));
                // numerically-stable sigmoid(2*alpha)
                float e = expf(-2.0f * fabsf(alpha));
                float r = 1.0f / (1.0f + e);
                float sig = (alpha >= 0.0f) ? r : (e * r);
                x[k] = tanhf(c * (sig - uvals[ki]));
            }
        }
    }

    // energy = sum_k (0.5 * (z @ M)_k + delta_k) * z_k
    float energy = 0.0f;
#pragma unroll
    for (int k = 0; k < DD; ++k) {
        const float* Mr = M + k * DD;
        float a0 = 0.f, a1 = 0.f, a2 = 0.f, a3 = 0.f;
#pragma unroll
        for (int j = 0; j < DD; j += 4) {
            a0 = fmaf(Mr[j + 0], x[j + 0], a0);
            a1 = fmaf(Mr[j + 1], x[j + 1], a1);
            a2 = fmaf(Mr[j + 2], x[j + 2], a2);
            a3 = fmaf(Mr[j + 3], x[j + 3], a3);
        }
        float dot = (a0 + a1) + (a2 + a3);
        energy = fmaf(0.5f * dot + delta[k], x[k], energy);
    }

    float4* zo = (float4*)(out + (size_t)b * DD);
#pragma unroll
    for (int i = 0; i < DD / 4; ++i) {
        zo[i] = make_float4(x[4 * i + 0], x[4 * i + 1], x[4 * i + 2], x[4 * i + 3]);
    }
    out[(size_t)B * DD + b] = energy;
}

extern "C" void kernel_launch(void* const* d_in, const int* in_sizes, int n_in,
                              void* d_out, int out_size, void* d_ws, size_t ws_size,
                              hipStream_t stream) {
    // setup_inputs order: inputs(B,1)[unused], Q(2016), delta(64), x0(B*64),
    // u(L*B*64), n_layers(1 int), const(1 int)
    const float* Q     = (const float*)d_in[1];
    const float* delta = (const float*)d_in[2];
    const float* x0    = (const float*)d_in[3];
    const float* u     = (const float*)d_in[4];
    const int*   nl    = (const int*)d_in[5];
    const int*   cc    = (const int*)d_in[6];
    float* M = (float*)d_ws;  // 64*64*4 = 16 KB scratch
    int B = in_sizes[3] / DD;

    build_M_kernel<<<(DD * DD + 255) / 256, 256, 0, stream>>>(Q, M);
    ising_main<<<(B + 255) / 256, 256, 0, stream>>>(M, delta, x0, u, nl, cc,
                                                    (float*)d_out, B);
}

// Round 2
// 3453.096 us; speedup vs baseline: 1.3221x; 1.3221x over previous
//
#include <hip/hip_runtime.h>

#define DD 64
#define HALF 32          // columns staged per LDS chunk
#define STRIDE 33        // LDS row stride in floats: bank = (row+col)%32 -> conflict-free

// Build symmetric coupling matrix M (64x64) from packed strict-lower-triangle Q.
__global__ void build_M_kernel(const float* __restrict__ Q, float* __restrict__ M) {
    int idx = blockIdx.x * 256 + threadIdx.x;
    if (idx < DD * DD) {
        int r = idx >> 6;
        int c = idx & 63;
        float v = 0.0f;
        if (r > c)      v = Q[(r * (r - 1)) / 2 + c];
        else if (c > r) v = Q[(c * (c - 1)) / 2 + r];
        M[idx] = v;
    }
}

__device__ __forceinline__ float fast_sigmoid2(float alpha) {
    // sigmoid(2*alpha), numerically stable, v_exp_f32 + v_rcp_f32
    float e = __expf(-2.0f * fabsf(alpha));
    float r = __builtin_amdgcn_rcpf(1.0f + e);
    return (alpha >= 0.0f) ? r : e * r;
}

__device__ __forceinline__ float fast_tanh(float t) {
    float a = fabsf(t);
    float e = __expf(-2.0f * a);
    float r = (1.0f - e) * __builtin_amdgcn_rcpf(1.0f + e);
    return copysignf(r, t);
}

// One thread per chain; x[64] in VGPRs; M/delta reads wave-uniform (scalar).
// All global traffic for u/x0/z goes through coalesced float4 <-> LDS staging.
__global__ __launch_bounds__(256, 4) void ising_main(
    const float* __restrict__ M,       // 64x64 symmetric, diag 0 (in d_ws)
    const float* __restrict__ delta,   // 64
    const float* __restrict__ x0,      // B*64
    const float* __restrict__ u,       // L*B*64
    const int* __restrict__ n_layers_p,
    const int* __restrict__ const_p,
    float* __restrict__ out,           // B*64 (z) then B (energy)
    int B)
{
    __shared__ float s_buf[256 * STRIDE];   // 33,792 B

    const int t  = threadIdx.x;
    const int b0 = blockIdx.x * 256;
    const int b  = b0 + t;
    const int L = n_layers_p[0];
    const float c = (float)const_p[0];

    float x[DD];

    // ---- staged, coalesced x0 load: two 256x32 chunks ----
#pragma unroll
    for (int ch = 0; ch < 2; ++ch) {
        // cooperative load: 256 rows x 32 floats = 2048 float4, 8 per thread
#pragma unroll
        for (int it = 0; it < 8; ++it) {
            int g = it * 256 + t;          // float4 index in chunk
            int r = g >> 3;                // 8 float4 per row
            int q = g & 7;
            float4 v = *(const float4*)(x0 + (size_t)(b0 + r) * DD + ch * HALF + q * 4);
            float* d = s_buf + r * STRIDE + q * 4;
            d[0] = v.x; d[1] = v.y; d[2] = v.z; d[3] = v.w;
        }
        __syncthreads();
#pragma unroll
        for (int j = 0; j < HALF; ++j)
            x[ch * HALF + j] = s_buf[t * STRIDE + j];
        __syncthreads();
    }

    // ---- sweeps ----
    for (int l = 0; l < L; ++l) {
        const float* ub = u + ((size_t)l * B + b0) * DD;
#pragma unroll
        for (int ch = 0; ch < 2; ++ch) {
            // stage u chunk (cols ch*32 .. ch*32+31) coalesced
#pragma unroll
            for (int it = 0; it < 8; ++it) {
                int g = it * 256 + t;
                int r = g >> 3;
                int q = g & 7;
                float4 v = *(const float4*)(ub + (size_t)r * DD + ch * HALF + q * 4);
                float* d = s_buf + r * STRIDE + q * 4;
                d[0] = v.x; d[1] = v.y; d[2] = v.z; d[3] = v.w;
            }
            __syncthreads();

#pragma unroll
            for (int j = 0; j < HALF; ++j) {
                const int k = ch * HALF + j;
                const float* Mr = M + k * DD;
                float a0 = 0.f, a1 = 0.f, a2 = 0.f, a3 = 0.f;
#pragma unroll
                for (int jj = 0; jj < DD; jj += 4) {
                    a0 = fmaf(Mr[jj + 0], x[jj + 0], a0);
                    a1 = fmaf(Mr[jj + 1], x[jj + 1], a1);
                    a2 = fmaf(Mr[jj + 2], x[jj + 2], a2);
                    a3 = fmaf(Mr[jj + 3], x[jj + 3], a3);
                }
                float alpha = delta[k] + ((a0 + a1) + (a2 + a3));
                float uk = s_buf[t * STRIDE + j];
                x[k] = fast_tanh(c * (fast_sigmoid2(alpha) - uk));
            }
            __syncthreads();
        }
    }

    // ---- energy ----
    float energy = 0.0f;
#pragma unroll
    for (int k = 0; k < DD; ++k) {
        const float* Mr = M + k * DD;
        float a0 = 0.f, a1 = 0.f, a2 = 0.f, a3 = 0.f;
#pragma unroll
        for (int jj = 0; jj < DD; jj += 4) {
            a0 = fmaf(Mr[jj + 0], x[jj + 0], a0);
            a1 = fmaf(Mr[jj + 1], x[jj + 1], a1);
            a2 = fmaf(Mr[jj + 2], x[jj + 2], a2);
            a3 = fmaf(Mr[jj + 3], x[jj + 3], a3);
        }
        float dot = (a0 + a1) + (a2 + a3);
        energy = fmaf(0.5f * dot + delta[k], x[k], energy);
    }

    // ---- staged, coalesced z store ----
#pragma unroll
    for (int ch = 0; ch < 2; ++ch) {
#pragma unroll
        for (int j = 0; j < HALF; ++j)
            s_buf[t * STRIDE + j] = x[ch * HALF + j];
        __syncthreads();
#pragma unroll
        for (int it = 0; it < 8; ++it) {
            int g = it * 256 + t;
            int r = g >> 3;
            int q = g & 7;
            const float* s = s_buf + r * STRIDE + q * 4;
            float4 v = make_float4(s[0], s[1], s[2], s[3]);
            *(float4*)(out + (size_t)(b0 + r) * DD + ch * HALF + q * 4) = v;
        }
        __syncthreads();
    }

    out[(size_t)B * DD + b] = energy;
}

extern "C" void kernel_launch(void* const* d_in, const int* in_sizes, int n_in,
                              void* d_out, int out_size, void* d_ws, size_t ws_size,
                              hipStream_t stream) {
    // setup_inputs order: inputs(B,1)[unused], Q(2016), delta(64), x0(B*64),
    // u(L*B*64), n_layers(1 int), const(1 int)
    const float* Q     = (const float*)d_in[1];
    const float* delta = (const float*)d_in[2];
    const float* x0    = (const float*)d_in[3];
    const float* u     = (const float*)d_in[4];
    const int*   nl    = (const int*)d_in[5];
    const int*   cc    = (const int*)d_in[6];
    float* M = (float*)d_ws;  // 16 KB scratch
    int B = in_sizes[3] / DD;

    build_M_kernel<<<(DD * DD + 255) / 256, 256, 0, stream>>>(Q, M);
    ising_main<<<B / 256, 256, 0, stream>>>(M, delta, x0, u, nl, cc,
                                            (float*)d_out, B);
}

// Round 3
// 3116.962 us; speedup vs baseline: 1.4646x; 1.1078x over previous
//
#include <hip/hip_runtime.h>

#define DD 64
#define HALF 32          // columns staged per LDS chunk
#define STRIDE 33        // LDS row stride: bank=(row+col)%32 -> conflict-free

// Build symmetric coupling matrix M (64x64) from packed strict-lower-triangle Q.
__global__ void build_M_kernel(const float* __restrict__ Q, float* __restrict__ M) {
    int idx = blockIdx.x * 256 + threadIdx.x;
    if (idx < DD * DD) {
        int r = idx >> 6;
        int c = idx & 63;
        float v = 0.0f;
        if (r > c)      v = Q[(r * (r - 1)) / 2 + c];
        else if (c > r) v = Q[(c * (c - 1)) / 2 + r];
        M[idx] = v;
    }
}

__device__ __forceinline__ float fast_sigmoid2(float alpha) {
    float e = __expf(-2.0f * fabsf(alpha));
    float r = __builtin_amdgcn_rcpf(1.0f + e);
    return (alpha >= 0.0f) ? r : e * r;
}

__device__ __forceinline__ float fast_tanh(float t) {
    float a = fabsf(t);
    float e = __expf(-2.0f * a);
    float r = (1.0f - e) * __builtin_amdgcn_rcpf(1.0f + e);
    return copysignf(r, t);
}

// ---- one Gauss-Seidel step, K compile-time => all x[] indices constant ----
template<int K>
__device__ __forceinline__ void gs_step(float (&x)[DD],
        const float* __restrict__ M, const float* __restrict__ delta,
        float c, const float* __restrict__ s_u)
{
    const float* Mr = M + K * DD;
    float a0 = 0.f, a1 = 0.f, a2 = 0.f, a3 = 0.f;
#pragma unroll
    for (int j = 0; j < DD; j += 4) {
        a0 = fmaf(Mr[j + 0], x[j + 0], a0);
        a1 = fmaf(Mr[j + 1], x[j + 1], a1);
        a2 = fmaf(Mr[j + 2], x[j + 2], a2);
        a3 = fmaf(Mr[j + 3], x[j + 3], a3);
    }
    float alpha = delta[K] + ((a0 + a1) + (a2 + a3));
    float uk = s_u[K & (HALF - 1)];
    x[K] = fast_tanh(c * (fast_sigmoid2(alpha) - uk));
}

template<int K, int KEND>
struct SweepChunk {
    static __device__ __forceinline__ void run(float (&x)[DD],
        const float* __restrict__ M, const float* __restrict__ delta,
        float c, const float* __restrict__ s_u)
    {
        gs_step<K>(x, M, delta, c, s_u);
        SweepChunk<K + 1, KEND>::run(x, M, delta, c, s_u);
    }
};
template<int KEND>
struct SweepChunk<KEND, KEND> {
    static __device__ __forceinline__ void run(float (&)[DD],
        const float*, const float*, float, const float*) {}
};

// ---- energy term for row K ----
template<int K>
__device__ __forceinline__ float energy_step(const float (&x)[DD],
        const float* __restrict__ M, const float* __restrict__ delta)
{
    const float* Mr = M + K * DD;
    float a0 = 0.f, a1 = 0.f, a2 = 0.f, a3 = 0.f;
#pragma unroll
    for (int j = 0; j < DD; j += 4) {
        a0 = fmaf(Mr[j + 0], x[j + 0], a0);
        a1 = fmaf(Mr[j + 1], x[j + 1], a1);
        a2 = fmaf(Mr[j + 2], x[j + 2], a2);
        a3 = fmaf(Mr[j + 3], x[j + 3], a3);
    }
    float dot = (a0 + a1) + (a2 + a3);
    return (0.5f * dot + delta[K]) * x[K];
}

template<int K, int KEND>
struct EnergyAcc {
    static __device__ __forceinline__ float run(const float (&x)[DD],
        const float* __restrict__ M, const float* __restrict__ delta)
    {
        return energy_step<K>(x, M, delta) + EnergyAcc<K + 1, KEND>::run(x, M, delta);
    }
};
template<int KEND>
struct EnergyAcc<KEND, KEND> {
    static __device__ __forceinline__ float run(const float (&)[DD],
        const float*, const float*) { return 0.0f; }
};

// ---- x <-> LDS row copies, constant indices via recursion ----
template<int CH, int J>
struct LoadX {
    static __device__ __forceinline__ void run(float (&x)[DD], const float* __restrict__ s_row) {
        x[CH * HALF + J] = s_row[J];
        LoadX<CH, J + 1>::run(x, s_row);
    }
};
template<int CH>
struct LoadX<CH, HALF> {
    static __device__ __forceinline__ void run(float (&)[DD], const float*) {}
};

template<int CH, int J>
struct StoreX {
    static __device__ __forceinline__ void run(const float (&x)[DD], float* __restrict__ s_row) {
        s_row[J] = x[CH * HALF + J];
        StoreX<CH, J + 1>::run(x, s_row);
    }
};
template<int CH>
struct StoreX<CH, HALF> {
    static __device__ __forceinline__ void run(const float (&)[DD], float*) {}
};

// ---- cooperative 256-row x 32-col global<->LDS staging ----
__device__ __forceinline__ void stage_chunk(const float* __restrict__ gsrc,
                                            float* __restrict__ s_buf, int t)
{
#pragma unroll
    for (int it = 0; it < 8; ++it) {
        int g = it * 256 + t;
        int r = g >> 3;
        int q = g & 7;
        float4 v = *(const float4*)(gsrc + (size_t)r * DD + q * 4);
        float* d = s_buf + r * STRIDE + q * 4;
        d[0] = v.x; d[1] = v.y; d[2] = v.z; d[3] = v.w;
    }
}

__device__ __forceinline__ void unstage_chunk(float* __restrict__ gdst,
                                              const float* __restrict__ s_buf, int t)
{
#pragma unroll
    for (int it = 0; it < 8; ++it) {
        int g = it * 256 + t;
        int r = g >> 3;
        int q = g & 7;
        const float* s = s_buf + r * STRIDE + q * 4;
        *(float4*)(gdst + (size_t)r * DD + q * 4) = make_float4(s[0], s[1], s[2], s[3]);
    }
}

__global__ __launch_bounds__(256, 3) void ising_main(
    const float* __restrict__ M,       // 64x64 symmetric, diag 0 (in d_ws)
    const float* __restrict__ delta,   // 64
    const float* __restrict__ x0,      // B*64
    const float* __restrict__ u,       // L*B*64
    const int* __restrict__ n_layers_p,
    const int* __restrict__ const_p,
    float* __restrict__ out,           // B*64 (z) then B (energy)
    int B)
{
    __shared__ float s_buf[256 * STRIDE];   // 33,792 B

    const int t  = threadIdx.x;
    const int b0 = blockIdx.x * 256;
    const int b  = b0 + t;
    const int L = n_layers_p[0];
    const float c = (float)const_p[0];

    float x[DD];
    float* s_row = s_buf + t * STRIDE;

    // ---- staged, coalesced x0 load ----
    stage_chunk(x0 + (size_t)b0 * DD + 0, s_buf, t);
    __syncthreads();
    LoadX<0, 0>::run(x, s_row);
    __syncthreads();
    stage_chunk(x0 + (size_t)b0 * DD + HALF, s_buf, t);
    __syncthreads();
    LoadX<1, 0>::run(x, s_row);
    __syncthreads();

    // ---- sweeps ----
    for (int l = 0; l < L; ++l) {
        const float* ub = u + ((size_t)l * B + b0) * DD;
        stage_chunk(ub, s_buf, t);
        __syncthreads();
        SweepChunk<0, HALF>::run(x, M, delta, c, s_row);
        __syncthreads();
        stage_chunk(ub + HALF, s_buf, t);
        __syncthreads();
        SweepChunk<HALF, DD>::run(x, M, delta, c, s_row);
        __syncthreads();
    }

    // ---- energy ----
    float energy = EnergyAcc<0, DD>::run(x, M, delta);

    // ---- staged, coalesced z store ----
    StoreX<0, 0>::run(x, s_row);
    __syncthreads();
    unstage_chunk(out + (size_t)b0 * DD + 0, s_buf, t);
    __syncthreads();
    StoreX<1, 0>::run(x, s_row);
    __syncthreads();
    unstage_chunk(out + (size_t)b0 * DD + HALF, s_buf, t);

    out[(size_t)B * DD + b] = energy;
}

extern "C" void kernel_launch(void* const* d_in, const int* in_sizes, int n_in,
                              void* d_out, int out_size, void* d_ws, size_t ws_size,
                              hipStream_t stream) {
    // setup_inputs order: inputs(B,1)[unused], Q(2016), delta(64), x0(B*64),
    // u(L*B*64), n_layers(1 int), const(1 int)
    const float* Q     = (const float*)d_in[1];
    const float* delta = (const float*)d_in[2];
    const float* x0    = (const float*)d_in[3];
    const float* u     = (const float*)d_in[4];
    const int*   nl    = (const int*)d_in[5];
    const int*   cc    = (const int*)d_in[6];
    float* M = (float*)d_ws;  // 16 KB scratch
    int B = in_sizes[3] / DD;

    build_M_kernel<<<(DD * DD + 255) / 256, 256, 0, stream>>>(Q, M);
    ising_main<<<B / 256, 256, 0, stream>>>(M, delta, x0, u, nl, cc,
                                            (float*)d_out, B);
}